// Round 6
// baseline (158.050 us; speedup 1.0000x reference)
//
#include <hip/hip_runtime.h>

#define T_LEN   1048576
#define K1B     1024                // K1 blocks, 1024 elems each
#define BLK     256
#define SEG     256                 // rows per output block
#define NSEG    (T_LEN / SEG)       // 4096 segments
#define MAXO    25
#define CLAMP_HI 24.0f
#define BIGF    1e30f

typedef float f4v __attribute__((ext_vector_type(4)));

// Saturating-add function f(c) = min(max(c + a, l), h); closed under composition.
struct Trip { float a, l, h; };

__device__ __forceinline__ Trip comb(Trip x, Trip y) {   // apply x first, then y
    Trip r;
    r.a = x.a + y.a;
    r.l = fmaxf(x.l + y.a, y.l);
    r.h = fminf(fmaxf(x.h + y.a, y.l), y.h);
    return r;
}
__device__ __forceinline__ float applyT(Trip p, float c) {
    return fminf(fmaxf(c + p.a, p.l), p.h);
}
__device__ __forceinline__ Trip shflUpTrip(Trip v, int off) {
    Trip r;
    r.a = __shfl_up(v.a, off, 64);
    r.l = __shfl_up(v.l, off, 64);
    r.h = __shfl_up(v.h, off, 64);
    return r;
}

// ---- K1: per-segment saturating-add triples (wave = one 256-elem segment) --
__global__ __launch_bounds__(BLK)
void k1_seg(const int* __restrict__ seq, const float* __restrict__ delta,
            float* __restrict__ tri) {
    __shared__ float dl[16];
    const int tid = threadIdx.x, lane = tid & 63, wid = tid >> 6;

    if (tid < 16) dl[tid] = delta[tid];
    __syncthreads();

    const int4 s4 = *(const int4*)(seq + blockIdx.x * 1024 + tid * 4);
    Trip t = {dl[s4.x], 0.0f, CLAMP_HI};
    { Trip e = {dl[s4.y], 0.0f, CLAMP_HI}; t = comb(t, e); }
    { Trip e = {dl[s4.z], 0.0f, CLAMP_HI}; t = comb(t, e); }
    { Trip e = {dl[s4.w], 0.0f, CLAMP_HI}; t = comb(t, e); }

#pragma unroll
    for (int off = 1; off < 64; off <<= 1) {
        Trip o = shflUpTrip(t, off);
        if (lane >= off) t = comb(o, t);
    }
    if (lane == 63) {
        const int sid = blockIdx.x * 4 + wid;
        tri[3 * sid + 0] = t.a;
        tri[3 * sid + 1] = t.l;
        tri[3 * sid + 2] = t.h;
    }
}

// ---- K2: redundant per-block entry scan + per-row softmax + float4 writes --
__global__ __launch_bounds__(BLK)
void k2_out(const int* __restrict__ seq, const float* __restrict__ delta,
            const float* __restrict__ bias, const float* __restrict__ scale,
            const float* __restrict__ tri, float* __restrict__ out) {
    __shared__ __align__(16) float tile[SEG * MAXO];     // 25600 B
    __shared__ Trip agg[4];
    __shared__ float dl[16], bs[MAXO];
    __shared__ float centry;

    const int tid = threadIdx.x, lane = tid & 63, wid = tid >> 6;
    const int bid = blockIdx.x;

    // issue all global loads up front
    if (tid < 16)   dl[tid] = delta[tid];
    if (tid < MAXO) bs[tid] = bias[tid];
    const float sfac = scale[0];
    const int s = seq[bid * SEG + tid];

    // ---- phase A: entry counter for segment bid (scan of 4096 triples) ----
    f4v f[12];                              // 16 triples = 48 floats
    const f4v* p = (const f4v*)(tri + tid * 48);
#pragma unroll
    for (int i = 0; i < 12; ++i) f[i] = p[i];
    const float* fp = (const float*)f;

    Trip loc[16];
#pragma unroll
    for (int k = 0; k < 16; ++k)
        loc[k] = {fp[3 * k], fp[3 * k + 1], fp[3 * k + 2]};

    Trip incl = loc[0];
#pragma unroll
    for (int k = 1; k < 16; ++k) incl = comb(incl, loc[k]);

#pragma unroll
    for (int off = 1; off < 64; off <<= 1) {
        Trip o = shflUpTrip(incl, off);
        if (lane >= off) incl = comb(o, incl);
    }
    if (lane == 63) agg[wid] = incl;
    __syncthreads();

    // UNIFORM: every lane computes its own 16-group's exclusive prefix.
    // (shuffles must NOT be under divergent control flow: ds_bpermute from
    //  an EXEC=0 lane returns zero — that was R5's bug.)
    Trip W = {0.0f, -BIGF, BIGF};                        // identity
    for (int w = 0; w < wid; ++w) W = comb(W, agg[w]);
    const Trip prev = shflUpTrip(incl, 1);               // scan value of tid-1
    const Trip E = (lane == 0) ? W : comb(W, prev);      // excl prefix of group tid

    {
        const int q = bid >> 4, r = bid & 15;
        if (tid == q) {                                  // no shuffles inside
            float c = applyT(E, 0.0f);
            for (int j = 0; j < r; ++j) c = applyT(loc[j], c);
            centry = c;
        }
    }
    __syncthreads();

    // ---- phase B: per-row counter via wave scan over this segment ----
    Trip t = {dl[s], 0.0f, CLAMP_HI};
#pragma unroll
    for (int off = 1; off < 64; off <<= 1) {
        Trip o = shflUpTrip(t, off);
        if (lane >= off) t = comb(o, t);
    }
    if (lane == 63) agg[wid] = t;
    __syncthreads();

    float cb = centry;
    for (int w = 0; w < wid; ++w) cb = applyT(agg[w], cb);
    const float c = applyT(t, cb);                       // counter for row tid

    // softmax without max-subtraction (logits <= ~0.4, fp32 safe)
    float ev[MAXO];
    float sum = 0.0f;
#pragma unroll
    for (int j = 0; j < MAXO; ++j) {
        ev[j] = __expf(fmaf(-sfac, fabsf((float)j - c), bs[j]));
        sum += ev[j];
    }
    const float r = 1.0f / sum;
#pragma unroll
    for (int j = 0; j < MAXO; ++j)                       // stride-25: conflict-free
        tile[tid * MAXO + j] = ev[j] * r;
    __syncthreads();

    const f4v* tp = (const f4v*)tile;
    f4v* op = (f4v*)(out + (size_t)bid * SEG * MAXO);
#pragma unroll
    for (int i = tid; i < SEG * MAXO / 4; i += BLK)      // 1600 float4s
        op[i] = tp[i];
}

extern "C" void kernel_launch(void* const* d_in, const int* in_sizes, int n_in,
                              void* d_out, int out_size, void* d_ws, size_t ws_size,
                              hipStream_t stream) {
    const int*   seq   = (const int*)d_in[0];
    const float* delta = (const float*)d_in[1];
    const float* bias  = (const float*)d_in[2];
    const float* scale = (const float*)d_in[3];
    float* out = (float*)d_out;

    float* tri = (float*)d_ws;                   // NSEG*3 floats = 48 KB

    k1_seg<<<K1B, BLK, 0, stream>>>(seq, delta, tri);
    k2_out<<<NSEG, BLK, 0, stream>>>(seq, delta, bias, scale, tri, out);
}

// Round 7
// 129.381 us; speedup vs baseline: 1.2216x; 1.2216x over previous
//
#include <hip/hip_runtime.h>

#define T_LEN   1048576
#define K1B     1024                // K1 blocks, 1024 elems each
#define BLK     256
#define SEG     256                 // rows per output block
#define NSEG    (T_LEN / SEG)       // 4096 segments
#define MAXO    25
#define CLAMP_HI 24.0f
#define BIGF    1e30f

typedef float f4v __attribute__((ext_vector_type(4)));

// Saturating-add function f(c) = min(max(c + a, l), h); closed under composition.
struct Trip { float a, l, h; };

__device__ __forceinline__ Trip comb(Trip x, Trip y) {   // apply x first, then y
    Trip r;
    r.a = x.a + y.a;
    r.l = fmaxf(x.l + y.a, y.l);
    r.h = fminf(fmaxf(x.h + y.a, y.l), y.h);
    return r;
}
__device__ __forceinline__ float applyT(Trip p, float c) {
    return fminf(fmaxf(c + p.a, p.l), p.h);
}
__device__ __forceinline__ Trip shflUpTrip(Trip v, int off) {
    Trip r;
    r.a = __shfl_up(v.a, off, 64);
    r.l = __shfl_up(v.l, off, 64);
    r.h = __shfl_up(v.h, off, 64);
    return r;
}

// ---- K1: per-segment saturating-add triples (wave = one 256-elem segment) --
__global__ __launch_bounds__(BLK)
void k1_seg(const int* __restrict__ seq, const float* __restrict__ delta,
            float* __restrict__ tri) {
    __shared__ float dl[16];
    const int tid = threadIdx.x, lane = tid & 63, wid = tid >> 6;

    if (tid < 16) dl[tid] = delta[tid];
    __syncthreads();

    const int4 s4 = *(const int4*)(seq + blockIdx.x * 1024 + tid * 4);
    Trip t = {dl[s4.x], 0.0f, CLAMP_HI};
    { Trip e = {dl[s4.y], 0.0f, CLAMP_HI}; t = comb(t, e); }
    { Trip e = {dl[s4.z], 0.0f, CLAMP_HI}; t = comb(t, e); }
    { Trip e = {dl[s4.w], 0.0f, CLAMP_HI}; t = comb(t, e); }

#pragma unroll
    for (int off = 1; off < 64; off <<= 1) {
        Trip o = shflUpTrip(t, off);
        if (lane >= off) t = comb(o, t);
    }
    if (lane == 63) {
        const int sid = blockIdx.x * 4 + wid;
        tri[3 * sid + 0] = t.a;
        tri[3 * sid + 1] = t.l;
        tri[3 * sid + 2] = t.h;
    }
}

// ---- K2: spill-free redundant entry scan + per-row softmax + f4 writes -----
__global__ __launch_bounds__(BLK)
void k2_out(const int* __restrict__ seq, const float* __restrict__ delta,
            const float* __restrict__ bias, const float* __restrict__ scale,
            const float* __restrict__ tri, float* __restrict__ out) {
    __shared__ __align__(16) float tile[SEG * MAXO];     // 25600 B
    __shared__ Trip agg[4];
    __shared__ float dl[16], bs[MAXO];
    __shared__ float centry;

    const int tid = threadIdx.x, lane = tid & 63, wid = tid >> 6;
    const int bid = blockIdx.x;

    // issue all global loads up front
    if (tid < 16)   dl[tid] = delta[tid];
    if (tid < MAXO) bs[tid] = bias[tid];
    const float sfac = scale[0];
    const int s = seq[bid * SEG + tid];

    // ---- phase A: entry counter for segment bid (scan of 4096 triples) ----
    // Fold 16 triples on the fly: never more than 3 f4v + running Trip live
    // (R6 kept a 16-Trip array -> scratch spill -> 3x WRITE_SIZE).
    const f4v* p = (const f4v*)(tri + tid * 48);
    Trip run;
#pragma unroll
    for (int ch = 0; ch < 4; ++ch) {
        const f4v fa = p[3 * ch], fb = p[3 * ch + 1], fc = p[3 * ch + 2];
        Trip t0 = {fa.x, fa.y, fa.z};
        Trip t1 = {fa.w, fb.x, fb.y};
        Trip t2 = {fb.z, fb.w, fc.x};
        Trip t3 = {fc.y, fc.z, fc.w};
        const Trip g = comb(comb(comb(t0, t1), t2), t3);
        run = (ch == 0) ? g : comb(run, g);
    }

    Trip incl = run;
#pragma unroll
    for (int off = 1; off < 64; off <<= 1) {
        Trip o = shflUpTrip(incl, off);
        if (lane >= off) incl = comb(o, incl);
    }
    if (lane == 63) agg[wid] = incl;
    __syncthreads();

    // UNIFORM control flow for all shuffles (EXEC=0 source lanes return 0).
    Trip W = {0.0f, -BIGF, BIGF};                        // identity
    for (int w = 0; w < wid; ++w) W = comb(W, agg[w]);
    const Trip prev = shflUpTrip(incl, 1);               // scan value of tid-1
    const Trip E = (lane == 0) ? W : comb(W, prev);      // excl prefix of group tid

    {
        const int q = bid >> 4, r = bid & 15;
        if (tid == q) {                                  // no shuffles inside
            float c = applyT(E, 0.0f);
            const float* tq = tri + 48 * q;              // re-read from L2
            for (int j = 0; j < r; ++j) {
                const Trip e = {tq[3 * j], tq[3 * j + 1], tq[3 * j + 2]};
                c = applyT(e, c);
            }
            centry = c;
        }
    }
    __syncthreads();

    // ---- phase B: per-row counter via wave scan over this segment ----
    Trip t = {dl[s], 0.0f, CLAMP_HI};
#pragma unroll
    for (int off = 1; off < 64; off <<= 1) {
        Trip o = shflUpTrip(t, off);
        if (lane >= off) t = comb(o, t);
    }
    if (lane == 63) agg[wid] = t;
    __syncthreads();

    float cb = centry;
    for (int w = 0; w < wid; ++w) cb = applyT(agg[w], cb);
    const float c = applyT(t, cb);                       // counter for row tid

    // softmax without max-subtraction (logits <= ~0.4, fp32 safe)
    float ev[MAXO];
    float sum = 0.0f;
#pragma unroll
    for (int j = 0; j < MAXO; ++j) {
        ev[j] = __expf(fmaf(-sfac, fabsf((float)j - c), bs[j]));
        sum += ev[j];
    }
    const float r = 1.0f / sum;
#pragma unroll
    for (int j = 0; j < MAXO; ++j)                       // stride-25: conflict-free
        tile[tid * MAXO + j] = ev[j] * r;
    __syncthreads();

    const f4v* tp = (const f4v*)tile;
    f4v* op = (f4v*)(out + (size_t)bid * SEG * MAXO);
#pragma unroll
    for (int i = tid; i < SEG * MAXO / 4; i += BLK)      // 1600 float4s
        op[i] = tp[i];
}

extern "C" void kernel_launch(void* const* d_in, const int* in_sizes, int n_in,
                              void* d_out, int out_size, void* d_ws, size_t ws_size,
                              hipStream_t stream) {
    const int*   seq   = (const int*)d_in[0];
    const float* delta = (const float*)d_in[1];
    const float* bias  = (const float*)d_in[2];
    const float* scale = (const float*)d_in[3];
    float* out = (float*)d_out;

    float* tri = (float*)d_ws;                   // NSEG*3 floats = 48 KB

    k1_seg<<<K1B, BLK, 0, stream>>>(seq, delta, tri);
    k2_out<<<NSEG, BLK, 0, stream>>>(seq, delta, bias, scale, tri, out);
}